// Round 11
// baseline (359.436 us; speedup 1.0000x reference)
//
#include <hip/hip_runtime.h>
#include <hip/hip_bf16.h>

#define NN 50000
#define EE 640000
#define LN_EPS 1e-5f
#define KD 272              // extended K (256 feat + deg + md + 1 + 13 zero pad)
#define KB 544              // bytes per feat row (KD*2)
#define NBK2 782            // buckets of 64 nodes (src >> 6)
#define CH 4096             // edges per binning block

typedef __bf16 bf16x8 __attribute__((ext_vector_type(8)));
typedef float f32x16 __attribute__((ext_vector_type(16)));

static __device__ __forceinline__ unsigned short f2bf(float f) {
    return __builtin_bit_cast(unsigned short, (__bf16)f);
}
static __device__ __forceinline__ float bflo(unsigned int u) {   // low bf16 of dword
    return __builtin_bit_cast(float, u << 16);
}
static __device__ __forceinline__ float bfhi(unsigned int u) {   // high bf16 of dword
    return __builtin_bit_cast(float, u & 0xffff0000u);
}

// ---- cast x to bf16 (gather source)
__global__ __launch_bounds__(256) void cast_x(const float* __restrict__ x,
                                              unsigned short* __restrict__ xbf) {
    int i = blockIdx.x * 256 + threadIdx.x;          // 8 elems per thread, 3125 blocks exact
    const float4* s = (const float4*)x + (size_t)i * 2;
    float4 a = s[0], b = s[1];
    unsigned short o[8] = { f2bf(a.x), f2bf(a.y), f2bf(a.z), f2bf(a.w),
                            f2bf(b.x), f2bf(b.y), f2bf(b.z), f2bf(b.w) };
    *(uint4*)(xbf + (size_t)i * 8) = *(const uint4*)o;
}

// ---- weight prep v4: ONE packed image per ct-tile (25600 B = LDS image, linear copy).
// Wimg[ct][0:8704]   : B1 tile [slot(34)][c(32)][e(8)] ; k=slot*8+e, col=ct*32+c
//                      k<258 -> W1[k][col]; k==258 -> b1[col]; else 0
// Wimg[ct][8704:12800]: B2 tile [slot(4)][c2(128)][e(8)] ; k=ct*32+slot*8+e -> W2[k][c2]
__global__ __launch_bounds__(256) void prep_weights(const float* __restrict__ W1,
                                                    const float* __restrict__ b1,
                                                    const float* __restrict__ W2,
                                                    unsigned short* __restrict__ Wimg) {
    int idx = blockIdx.x * 256 + threadIdx.x;        // < 204800 = 16*12800
    int ct = idx / 12800;
    int r = idx - ct * 12800;
    float v = 0.f;
    if (r < 8704) {
        int slot = r >> 8;           // 256 shorts per slot
        int c = (r >> 3) & 31;
        int e = r & 7;
        int k = slot * 8 + e;
        int col = ct * 32 + c;
        if (k < 258) v = W1[(size_t)k * 512 + col];
        else if (k == 258) v = b1[col];
    } else {
        int r2 = r - 8704;
        int slot = r2 >> 10;         // 1024 shorts per slot
        int c2 = (r2 >> 3) & 127;
        int e = r2 & 7;
        int k = ct * 32 + slot * 8 + e;
        v = W2[(size_t)k * 128 + c2];
    }
    Wimg[idx] = f2bf(v);
}

// ---- Prefix scan of int(degrees) over NN elements -> start[]; also seeds bucket cursors ----
__global__ __launch_bounds__(256) void scanA(const float* __restrict__ degrees,
                                             int* __restrict__ blocksum) {
    __shared__ int wsum[4];
    int i = blockIdx.x * 256 + threadIdx.x;
    int v = (i < NN) ? (int)(degrees[i] + 0.5f) : 0;
    int s = v;
    for (int d = 1; d < 64; d <<= 1) s += __shfl_xor(s, d, 64);
    if ((threadIdx.x & 63) == 0) wsum[threadIdx.x >> 6] = s;
    __syncthreads();
    if (threadIdx.x == 0) blocksum[blockIdx.x] = wsum[0] + wsum[1] + wsum[2] + wsum[3];
}

__global__ __launch_bounds__(256) void scanB(const int* __restrict__ blocksum,
                                             int* __restrict__ blockoff, int nb) {
    __shared__ int wsum[4];
    int tid = threadIdx.x;
    int v = (tid < nb) ? blocksum[tid] : 0;
    int lane = tid & 63, wid = tid >> 6;
    int inc = v;
    for (int d = 1; d < 64; d <<= 1) { int t = __shfl_up(inc, d, 64); if (lane >= d) inc += t; }
    if (lane == 63) wsum[wid] = inc;
    __syncthreads();
    int add = 0;
    for (int w = 0; w < wid; w++) add += wsum[w];
    inc += add;
    if (tid < nb) blockoff[tid] = inc - v;   // exclusive
}

__global__ __launch_bounds__(256) void scanC(const float* __restrict__ degrees,
                                             const int* __restrict__ blockoff,
                                             int* __restrict__ start,
                                             int* __restrict__ gcur) {
    __shared__ int wsum[4];
    int tid = threadIdx.x;
    int i = blockIdx.x * 256 + tid;
    int v = (i < NN) ? (int)(degrees[i] + 0.5f) : 0;
    int lane = tid & 63, wid = tid >> 6;
    int inc = v;
    for (int d = 1; d < 64; d <<= 1) { int t = __shfl_up(inc, d, 64); if (lane >= d) inc += t; }
    if (lane == 63) wsum[wid] = inc;
    __syncthreads();
    int add = blockoff[blockIdx.x];
    for (int w = 0; w < wid; w++) add += wsum[w];
    int excl = add + inc - v;
    if (i < NN) {
        start[i] = excl;
        if ((i & 63) == 0) gcur[i >> 6] = excl;   // bucket cursor = CSR start of its first node
    }
}

// ---- bin edges into bucket-major 4B records with LDS staging (coalesced writeout);
//      accumulate dist_sum via global atomics (200KB, L2-hot).
// record = dst(16b) | (src&63)<<16
__global__ __launch_bounds__(256) void bin_kernel(const int* __restrict__ ei,
                                                  const float* __restrict__ edist,
                                                  int* __restrict__ gcur,
                                                  unsigned* __restrict__ recs1,
                                                  float* __restrict__ dist) {
    __shared__ int cnt[NBK2], off[NBK2], gb[NBK2], c2[NBK2];
    __shared__ int wsum[4];
    __shared__ unsigned stage[CH];
    __shared__ int gtg[CH];
    int tid = threadIdx.x, lane = tid & 63, wid = tid >> 6;
    int e0 = blockIdx.x * CH;
    int nval = EE - e0; if (nval > CH) nval = CH;

    for (int i = tid; i < NBK2; i += 256) { cnt[i] = 0; c2[i] = 0; }
    __syncthreads();
#pragma unroll
    for (int k = 0; k < CH / 256; k++) {
        int e = e0 + k * 256 + tid;
        if (e < EE) atomicAdd(&cnt[ei[e] >> 6], 1);
    }
    __syncthreads();
    // exclusive scan of cnt -> off (4 elems/thread)
    {
        int v[4], s = 0;
#pragma unroll
        for (int j = 0; j < 4; j++) {
            int idx = tid * 4 + j;
            v[j] = (idx < NBK2) ? cnt[idx] : 0;
            s += v[j];
        }
        int inc = s;
        for (int d = 1; d < 64; d <<= 1) { int t = __shfl_up(inc, d, 64); if (lane >= d) inc += t; }
        if (lane == 63) wsum[wid] = inc;
        __syncthreads();
        int base = 0;
        for (int w = 0; w < wid; w++) base += wsum[w];
        int ex = base + inc - s;
#pragma unroll
        for (int j = 0; j < 4; j++) {
            int idx = tid * 4 + j;
            if (idx < NBK2) off[idx] = ex;
            ex += v[j];
        }
    }
    __syncthreads();
    // reserve global ranges
    for (int i = tid; i < NBK2; i += 256) {
        int c = cnt[i];
        gb[i] = c ? atomicAdd(&gcur[i], c) : 0;
    }
    __syncthreads();
    // stage records bucket-major; dist atomics
#pragma unroll
    for (int k = 0; k < CH / 256; k++) {
        int e = e0 + k * 256 + tid;
        if (e < EE) {
            int s = ei[e];
            int d = ei[EE + e];
            atomicAdd(dist + s, edist[e]);
            int b = s >> 6;
            int p = atomicAdd(&c2[b], 1);
            int slot = off[b] + p;
            stage[slot] = (unsigned)d | ((unsigned)(s & 63) << 16);
            gtg[slot] = gb[b] + p;
        }
    }
    __syncthreads();
    // coalesced-run writeout
    for (int i = tid; i < nval; i += 256)
        recs1[gtg[i]] = stage[i];
}

// ---- subsort: within each bucket, place records at exact per-node CSR slots (u16 dst)
__global__ __launch_bounds__(256) void subsort_kernel(const unsigned* __restrict__ recs1,
                                                      const int* __restrict__ start,
                                                      unsigned short* __restrict__ recs2) {
    __shared__ int cur[64];
    int bkt = blockIdx.x, tid = threadIdx.x;
    int bstart = start[bkt * 64];
    int bend = (bkt == NBK2 - 1) ? EE : start[(bkt + 1) * 64];
    if (tid < 64) {
        int node = bkt * 64 + tid;
        cur[tid] = (node < NN) ? start[node] : EE;
    }
    __syncthreads();
    for (int i = bstart + tid; i < bend; i += 256) {
        unsigned r = recs1[i];
        int p = atomicAdd(&cur[(r >> 16) & 63], 1);
        recs2[p] = (unsigned short)(r & 0xffffu);
    }
}

// ---- wave-per-node register aggregation + extended feat emit
__global__ __launch_bounds__(256) void aggfeat_kernel(const unsigned short* __restrict__ xbf,
                                                      const int* __restrict__ start,
                                                      const float* __restrict__ degrees,
                                                      const unsigned short* __restrict__ recs2,
                                                      const float* __restrict__ dist,
                                                      unsigned short* __restrict__ featbf) {
    int tid = threadIdx.x;
    int node = blockIdx.x * 4 + (tid >> 6);
    int lane = tid & 63;
    if (node >= NN) return;
    int st = start[node];
    int cnt = (int)(degrees[node] + 0.5f);
    float a0 = 0.f, a1 = 0.f;
    for (int base = 0; base < cnt; base += 64) {
        int rem = cnt - base;
        int nv = rem < 64 ? rem : 64;
        int didx = (lane < nv) ? (int)recs2[st + base + lane] : 0;
        int j = 0;
        for (; j + 4 <= nv; j += 4) {
            int d0 = __shfl(didx, j,     64);
            int d1 = __shfl(didx, j + 1, 64);
            int d2 = __shfl(didx, j + 2, 64);
            int d3 = __shfl(didx, j + 3, 64);
            unsigned x0 = *(const unsigned*)(xbf + (size_t)d0 * 128 + lane * 2);
            unsigned x1 = *(const unsigned*)(xbf + (size_t)d1 * 128 + lane * 2);
            unsigned x2 = *(const unsigned*)(xbf + (size_t)d2 * 128 + lane * 2);
            unsigned x3 = *(const unsigned*)(xbf + (size_t)d3 * 128 + lane * 2);
            a0 += bflo(x0) + bflo(x1) + bflo(x2) + bflo(x3);
            a1 += bfhi(x0) + bfhi(x1) + bfhi(x2) + bfhi(x3);
        }
        for (; j < nv; j++) {
            int dj = __shfl(didx, j, 64);
            unsigned xv = *(const unsigned*)(xbf + (size_t)dj * 128 + lane * 2);
            a0 += bflo(xv);
            a1 += bfhi(xv);
        }
    }
    float dg = degrees[node];
    float degc = fmaxf(dg, 1.0f);
    float inv = 1.0f / degc;
    unsigned short* row = featbf + (size_t)node * KD;
    *(unsigned int*)(row + lane * 2) = *(const unsigned int*)(xbf + (size_t)node * 128 + lane * 2);
    unsigned short o2[2] = { f2bf(a0 * inv), f2bf(a1 * inv) };
    *(unsigned int*)(row + 128 + lane * 2) = *(const unsigned int*)o2;
    if (lane < 4) {
        unsigned short t4[4] = { 0, 0, 0, 0 };
        if (lane == 0) { t4[0] = f2bf(dg); t4[1] = f2bf(dist[node] * inv); t4[2] = f2bf(1.0f); }
        *(uint2*)(row + 256 + lane * 4) = *(const uint2*)t4;
    }
}

// ---- fused MLP+LN v4: 64 rows/block (2 waves x 32), 16 ct-tiles of 32 W1-cols,
// k-major conflict-free LDS, double-buffered plain staging (load->reg early, ds_write late).
__global__ __launch_bounds__(128, 2) void fused_mlp_ln(const unsigned short* __restrict__ featbf,
                                                       const unsigned short* __restrict__ Wimg,
                                                       const float* __restrict__ x,
                                                       const float* __restrict__ b2,
                                                       const float* __restrict__ gamma,
                                                       const float* __restrict__ beta,
                                                       float* __restrict__ out) {
    __shared__ __align__(16) unsigned char lds[51200];   // 2 x 25600 double buffer

    int tid = threadIdx.x;
    int wave = tid >> 6, lane = tid & 63;
    int ln = lane & 31, hi = lane >> 5;
    int rowbase = blockIdx.x * 64 + wave * 32;
    int gr = rowbase + ln;

    // feat fragments: lane holds feat[gr][k = ks*16 + hi*8 + e]
    bf16x8 ffr[17];
    if (gr < NN) {
        const unsigned char* fp = (const unsigned char*)featbf + (size_t)gr * KB + hi * 16;
#pragma unroll
        for (int ks = 0; ks < 17; ks++)
            ffr[ks] = *(const bf16x8*)(fp + ks * 32);
    } else {
#pragma unroll
        for (int ks = 0; ks < 17; ks++) ffr[ks] = (bf16x8)(__bf16)0.0f;
    }

    f32x16 acc2[4] = {};    // out^T: lane holds out[c][gr], c = at*32 + (reg&3)+8*(reg>>2)+4*hi

    const uint4* img = (const uint4*)Wimg;     // 16 ct-tiles x 1600 uint4
    uint4 pre[13];
    // prologue: stage tile 0 into buffer A
#pragma unroll
    for (int j = 0; j < 13; j++) {
        int idx = tid + j * 128;
        if (idx < 1600) pre[j] = img[idx];
    }
    {
        uint4* lb = (uint4*)lds;
#pragma unroll
        for (int j = 0; j < 13; j++) {
            int idx = tid + j * 128;
            if (idx < 1600) lb[idx] = pre[j];
        }
    }
    __syncthreads();

    for (int ct = 0; ct < 16; ct++) {
        const unsigned char* cur = lds + (ct & 1) * 25600;
        unsigned char* nxt = lds + ((ct + 1) & 1) * 25600;

        // issue next-tile loads early (hidden under compute)
        if (ct < 15) {
            const uint4* src = img + (ct + 1) * 1600;
#pragma unroll
            for (int j = 0; j < 13; j++) {
                int idx = tid + j * 128;
                if (idx < 1600) pre[j] = src[idx];
            }
        }

        // GEMM1: one 32-col tile, K=272
        f32x16 acc1 = {};
#pragma unroll
        for (int ks = 0; ks < 17; ks++) {
            bf16x8 af = *(const bf16x8*)(cur + (2 * ks + hi) * 512 + ln * 16);
            acc1 = __builtin_amdgcn_mfma_f32_32x32x16_bf16(af, ffr[ks], acc1, 0, 0, 0);
        }

        // epilogue-1: relu + pack pairs. dw[g][i] = h cols {g*8+4hi+2i, +1} of this tile
        unsigned int dw[4][2];
#pragma unroll
        for (int g = 0; g < 4; g++)
#pragma unroll
            for (int i = 0; i < 2; i++) {
                float lo = fmaxf(acc1[g * 4 + 2 * i], 0.f);
                float hf = fmaxf(acc1[g * 4 + 2 * i + 1], 0.f);
                dw[g][i] = (unsigned int)f2bf(lo) | ((unsigned int)f2bf(hf) << 16);
            }

        // GEMM2: 2 k-windows of 16; B-frag assembled via one lane<->lane^32 exchange
        const unsigned char* B2c = cur + 17408;
#pragma unroll
        for (int w = 0; w < 2; w++) {
            unsigned int sL0 = dw[2 * w][0],     sL1 = dw[2 * w][1];
            unsigned int sH0 = dw[2 * w + 1][0], sH1 = dw[2 * w + 1][1];
            unsigned int send0 = hi ? sL0 : sH0;
            unsigned int send1 = hi ? sL1 : sH1;
            unsigned int r0 = (unsigned int)__shfl_xor((int)send0, 32, 64);
            unsigned int r1 = (unsigned int)__shfl_xor((int)send1, 32, 64);
            uint4 fd;
            fd.x = hi ? r0 : sL0;
            fd.y = hi ? r1 : sL1;
            fd.z = hi ? sH0 : r0;
            fd.w = hi ? sH1 : r1;
            bf16x8 hfr = __builtin_bit_cast(bf16x8, fd);
#pragma unroll
            for (int at = 0; at < 4; at++) {
                bf16x8 a2 = *(const bf16x8*)(B2c + (2 * w + hi) * 2048 + (at * 32 + ln) * 16);
                acc2[at] = __builtin_amdgcn_mfma_f32_32x32x16_bf16(a2, hfr, acc2[at], 0, 0, 0);
            }
        }

        // write next tile into the other buffer (safe: all waves passed the previous barrier,
        // so nobody is still reading nxt = the buffer last read in iteration ct-1)
        if (ct < 15) {
            uint4* lb = (uint4*)nxt;
#pragma unroll
            for (int j = 0; j < 13; j++) {
                int idx = tid + j * 128;
                if (idx < 1600) lb[idx] = pre[j];
            }
        }
        __syncthreads();   // next tile fully staged; current tile reads done block-wide
    }

    // epilogue-2: y = acc2 + b2 + x; LayerNorm across the lane pair (ln, ln+32); store
    bool rok = (gr < NN);
    float sum = 0.f, sq = 0.f;
#pragma unroll
    for (int at = 0; at < 4; at++)
#pragma unroll
        for (int g = 0; g < 4; g++) {
            int c0 = at * 32 + g * 8 + hi * 4;
            float4 bq = *(const float4*)(b2 + c0);
            float4 xq = rok ? *(const float4*)(x + (size_t)gr * 128 + c0) : make_float4(0, 0, 0, 0);
            float vb[4] = { bq.x, bq.y, bq.z, bq.w };
            float vx[4] = { xq.x, xq.y, xq.z, xq.w };
#pragma unroll
            for (int m = 0; m < 4; m++) {
                float v = acc2[at][g * 4 + m] + vb[m] + vx[m];
                acc2[at][g * 4 + m] = v;
                sum += v;
                sq += v * v;
            }
        }
    sum += __shfl_xor(sum, 32, 64);
    sq  += __shfl_xor(sq, 32, 64);
    float mu = sum * (1.0f / 128.0f);
    float var = sq * (1.0f / 128.0f) - mu * mu;
    float rs = rsqrtf(var + LN_EPS);
    if (rok) {
        float* orow = out + (size_t)gr * 128;
#pragma unroll
        for (int at = 0; at < 4; at++)
#pragma unroll
            for (int g = 0; g < 4; g++) {
                int c0 = at * 32 + g * 8 + hi * 4;
                float4 gq = *(const float4*)(gamma + c0);
                float4 be = *(const float4*)(beta + c0);
                float4 o;
                o.x = (acc2[at][g * 4 + 0] - mu) * rs * gq.x + be.x;
                o.y = (acc2[at][g * 4 + 1] - mu) * rs * gq.y + be.y;
                o.z = (acc2[at][g * 4 + 2] - mu) * rs * gq.z + be.z;
                o.w = (acc2[at][g * 4 + 3] - mu) * rs * gq.w + be.w;
                *(float4*)(orow + c0) = o;
            }
    }
}

extern "C" void kernel_launch(void* const* d_in, const int* in_sizes, int n_in,
                              void* d_out, int out_size, void* d_ws, size_t ws_size,
                              hipStream_t stream) {
    const float* x       = (const float*)d_in[0];
    const float* W1      = (const float*)d_in[1];
    const float* b1      = (const float*)d_in[2];
    const float* W2      = (const float*)d_in[3];
    const float* b2      = (const float*)d_in[4];
    const float* gamma   = (const float*)d_in[5];
    const float* beta    = (const float*)d_in[6];
    const int*   ei      = (const int*)d_in[7];
    const float* edist   = (const float*)d_in[8];
    const float* degrees = (const float*)d_in[9];
    float* out = (float*)d_out;

    char* ws = (char*)d_ws;
    size_t off = 0;
    auto alloc = [&](size_t bytes) {
        void* p = ws + off;
        off = (off + bytes + 255) & ~(size_t)255;
        return p;
    };
    unsigned* recs1         = (unsigned*)alloc((size_t)EE * 4);          // 2.56 MB
    unsigned short* recs2   = (unsigned short*)alloc((size_t)EE * 2);    // 1.28 MB
    int* start              = (int*)alloc((size_t)NN * 4);
    int* gcur               = (int*)alloc(NBK2 * 4);
    int* blocksum           = (int*)alloc(256 * 4);
    int* blockoff           = (int*)alloc(256 * 4);
    float* dist             = (float*)alloc((size_t)NN * 4);
    unsigned short* xbf     = (unsigned short*)alloc((size_t)NN * 128 * 2);
    unsigned short* featbf  = (unsigned short*)alloc((size_t)NN * KD * 2);
    unsigned short* Wimg    = (unsigned short*)alloc((size_t)204800 * 2); // 16 x 25600 B

    const int NB = (NN + 255) / 256;   // 196

    hipMemsetAsync(dist, 0, (size_t)NN * 4, stream);
    cast_x<<<3125, 256, 0, stream>>>(x, xbf);
    prep_weights<<<800, 256, 0, stream>>>(W1, b1, W2, Wimg);
    scanA<<<NB, 256, 0, stream>>>(degrees, blocksum);
    scanB<<<1, 256, 0, stream>>>(blocksum, blockoff, NB);
    scanC<<<NB, 256, 0, stream>>>(degrees, blockoff, start, gcur);
    bin_kernel<<<(EE + CH - 1) / CH, 256, 0, stream>>>(ei, edist, gcur, recs1, dist);
    subsort_kernel<<<NBK2, 256, 0, stream>>>(recs1, start, recs2);
    aggfeat_kernel<<<(NN + 3) / 4, 256, 0, stream>>>(xbf, start, degrees, recs2, dist, featbf);
    fused_mlp_ln<<<(NN + 63) / 64, 128, 0, stream>>>(featbf, Wimg, x, b2, gamma, beta, out);
}

// Round 12
// 268.305 us; speedup vs baseline: 1.3397x; 1.3397x over previous
//
#include <hip/hip_runtime.h>
#include <hip/hip_bf16.h>

#define NN 50000
#define EE 640000
#define LN_EPS 1e-5f
#define KD 272              // extended K (256 feat + deg + md + 1 + 13 zero pad)
#define KB 544              // bytes per feat row (KD*2)
#define NBK2 782            // buckets of 64 nodes (src >> 6)
#define CH 4096             // edges per binning block

typedef __bf16 bf16x8 __attribute__((ext_vector_type(8)));
typedef float f32x16 __attribute__((ext_vector_type(16)));

static __device__ __forceinline__ unsigned short f2bf(float f) {
    return __builtin_bit_cast(unsigned short, (__bf16)f);
}
static __device__ __forceinline__ float bflo(unsigned int u) {   // low bf16 of dword
    return __builtin_bit_cast(float, u << 16);
}
static __device__ __forceinline__ float bfhi(unsigned int u) {   // high bf16 of dword
    return __builtin_bit_cast(float, u & 0xffff0000u);
}

// ---- cast x to bf16 (gather source)
__global__ __launch_bounds__(256) void cast_x(const float* __restrict__ x,
                                              unsigned short* __restrict__ xbf) {
    int i = blockIdx.x * 256 + threadIdx.x;          // 8 elems per thread, 3125 blocks exact
    const float4* s = (const float4*)x + (size_t)i * 2;
    float4 a = s[0], b = s[1];
    unsigned short o[8] = { f2bf(a.x), f2bf(a.y), f2bf(a.z), f2bf(a.w),
                            f2bf(b.x), f2bf(b.y), f2bf(b.z), f2bf(b.w) };
    *(uint4*)(xbf + (size_t)i * 8) = *(const uint4*)o;
}

// ---- weight prep v4: ONE packed image per ct-tile (25600 B = LDS image, linear copy).
// Wimg[ct][0:8704]   : B1 tile [slot(34)][c(32)][e(8)] ; k=slot*8+e, col=ct*32+c
//                      k<258 -> W1[k][col]; k==258 -> b1[col]; else 0
// Wimg[ct][8704:12800]: B2 tile [slot(4)][c2(128)][e(8)] ; k=ct*32+slot*8+e -> W2[k][c2]
__global__ __launch_bounds__(256) void prep_weights(const float* __restrict__ W1,
                                                    const float* __restrict__ b1,
                                                    const float* __restrict__ W2,
                                                    unsigned short* __restrict__ Wimg) {
    int idx = blockIdx.x * 256 + threadIdx.x;        // < 204800 = 16*12800
    int ct = idx / 12800;
    int r = idx - ct * 12800;
    float v = 0.f;
    if (r < 8704) {
        int slot = r >> 8;           // 256 shorts per slot
        int c = (r >> 3) & 31;
        int e = r & 7;
        int k = slot * 8 + e;
        int col = ct * 32 + c;
        if (k < 258) v = W1[(size_t)k * 512 + col];
        else if (k == 258) v = b1[col];
    } else {
        int r2 = r - 8704;
        int slot = r2 >> 10;         // 1024 shorts per slot
        int c2 = (r2 >> 3) & 127;
        int e = r2 & 7;
        int k = ct * 32 + slot * 8 + e;
        v = W2[(size_t)k * 128 + c2];
    }
    Wimg[idx] = f2bf(v);
}

// ---- Prefix scan of int(degrees) over NN elements -> start[]; also seeds bucket cursors ----
__global__ __launch_bounds__(256) void scanA(const float* __restrict__ degrees,
                                             int* __restrict__ blocksum) {
    __shared__ int wsum[4];
    int i = blockIdx.x * 256 + threadIdx.x;
    int v = (i < NN) ? (int)(degrees[i] + 0.5f) : 0;
    int s = v;
    for (int d = 1; d < 64; d <<= 1) s += __shfl_xor(s, d, 64);
    if ((threadIdx.x & 63) == 0) wsum[threadIdx.x >> 6] = s;
    __syncthreads();
    if (threadIdx.x == 0) blocksum[blockIdx.x] = wsum[0] + wsum[1] + wsum[2] + wsum[3];
}

__global__ __launch_bounds__(256) void scanB(const int* __restrict__ blocksum,
                                             int* __restrict__ blockoff, int nb) {
    __shared__ int wsum[4];
    int tid = threadIdx.x;
    int v = (tid < nb) ? blocksum[tid] : 0;
    int lane = tid & 63, wid = tid >> 6;
    int inc = v;
    for (int d = 1; d < 64; d <<= 1) { int t = __shfl_up(inc, d, 64); if (lane >= d) inc += t; }
    if (lane == 63) wsum[wid] = inc;
    __syncthreads();
    int add = 0;
    for (int w = 0; w < wid; w++) add += wsum[w];
    inc += add;
    if (tid < nb) blockoff[tid] = inc - v;   // exclusive
}

__global__ __launch_bounds__(256) void scanC(const float* __restrict__ degrees,
                                             const int* __restrict__ blockoff,
                                             int* __restrict__ start,
                                             int* __restrict__ gcur) {
    __shared__ int wsum[4];
    int tid = threadIdx.x;
    int i = blockIdx.x * 256 + tid;
    int v = (i < NN) ? (int)(degrees[i] + 0.5f) : 0;
    int lane = tid & 63, wid = tid >> 6;
    int inc = v;
    for (int d = 1; d < 64; d <<= 1) { int t = __shfl_up(inc, d, 64); if (lane >= d) inc += t; }
    if (lane == 63) wsum[wid] = inc;
    __syncthreads();
    int add = blockoff[blockIdx.x];
    for (int w = 0; w < wid; w++) add += wsum[w];
    int excl = add + inc - v;
    if (i < NN) {
        start[i] = excl;
        if ((i & 63) == 0) gcur[i >> 6] = excl;   // bucket cursor = CSR start of its first node
    }
}

// ---- bin edges into bucket-major 4B records with LDS staging (coalesced writeout);
//      accumulate dist_sum via global atomics (200KB, L2-hot).
// record = dst(16b) | (src&63)<<16
__global__ __launch_bounds__(256) void bin_kernel(const int* __restrict__ ei,
                                                  const float* __restrict__ edist,
                                                  int* __restrict__ gcur,
                                                  unsigned* __restrict__ recs1,
                                                  float* __restrict__ dist) {
    __shared__ int cnt[NBK2], off[NBK2], gb[NBK2], c2[NBK2];
    __shared__ int wsum[4];
    __shared__ unsigned stage[CH];
    __shared__ int gtg[CH];
    int tid = threadIdx.x, lane = tid & 63, wid = tid >> 6;
    int e0 = blockIdx.x * CH;
    int nval = EE - e0; if (nval > CH) nval = CH;

    for (int i = tid; i < NBK2; i += 256) { cnt[i] = 0; c2[i] = 0; }
    __syncthreads();
#pragma unroll
    for (int k = 0; k < CH / 256; k++) {
        int e = e0 + k * 256 + tid;
        if (e < EE) atomicAdd(&cnt[ei[e] >> 6], 1);
    }
    __syncthreads();
    // exclusive scan of cnt -> off (4 elems/thread)
    {
        int v[4], s = 0;
#pragma unroll
        for (int j = 0; j < 4; j++) {
            int idx = tid * 4 + j;
            v[j] = (idx < NBK2) ? cnt[idx] : 0;
            s += v[j];
        }
        int inc = s;
        for (int d = 1; d < 64; d <<= 1) { int t = __shfl_up(inc, d, 64); if (lane >= d) inc += t; }
        if (lane == 63) wsum[wid] = inc;
        __syncthreads();
        int base = 0;
        for (int w = 0; w < wid; w++) base += wsum[w];
        int ex = base + inc - s;
#pragma unroll
        for (int j = 0; j < 4; j++) {
            int idx = tid * 4 + j;
            if (idx < NBK2) off[idx] = ex;
            ex += v[j];
        }
    }
    __syncthreads();
    // reserve global ranges
    for (int i = tid; i < NBK2; i += 256) {
        int c = cnt[i];
        gb[i] = c ? atomicAdd(&gcur[i], c) : 0;
    }
    __syncthreads();
    // stage records bucket-major; dist atomics
#pragma unroll
    for (int k = 0; k < CH / 256; k++) {
        int e = e0 + k * 256 + tid;
        if (e < EE) {
            int s = ei[e];
            int d = ei[EE + e];
            atomicAdd(dist + s, edist[e]);
            int b = s >> 6;
            int p = atomicAdd(&c2[b], 1);
            int slot = off[b] + p;
            stage[slot] = (unsigned)d | ((unsigned)(s & 63) << 16);
            gtg[slot] = gb[b] + p;
        }
    }
    __syncthreads();
    // coalesced-run writeout
    for (int i = tid; i < nval; i += 256)
        recs1[gtg[i]] = stage[i];
}

// ---- subsort: within each bucket, place records at exact per-node CSR slots (u16 dst)
__global__ __launch_bounds__(256) void subsort_kernel(const unsigned* __restrict__ recs1,
                                                      const int* __restrict__ start,
                                                      unsigned short* __restrict__ recs2) {
    __shared__ int cur[64];
    int bkt = blockIdx.x, tid = threadIdx.x;
    int bstart = start[bkt * 64];
    int bend = (bkt == NBK2 - 1) ? EE : start[(bkt + 1) * 64];
    if (tid < 64) {
        int node = bkt * 64 + tid;
        cur[tid] = (node < NN) ? start[node] : EE;
    }
    __syncthreads();
    for (int i = bstart + tid; i < bend; i += 256) {
        unsigned r = recs1[i];
        int p = atomicAdd(&cur[(r >> 16) & 63], 1);
        recs2[p] = (unsigned short)(r & 0xffffu);
    }
}

// ---- wave-per-node register aggregation + extended feat emit
__global__ __launch_bounds__(256) void aggfeat_kernel(const unsigned short* __restrict__ xbf,
                                                      const int* __restrict__ start,
                                                      const float* __restrict__ degrees,
                                                      const unsigned short* __restrict__ recs2,
                                                      const float* __restrict__ dist,
                                                      unsigned short* __restrict__ featbf) {
    int tid = threadIdx.x;
    int node = blockIdx.x * 4 + (tid >> 6);
    int lane = tid & 63;
    if (node >= NN) return;
    int st = start[node];
    int cnt = (int)(degrees[node] + 0.5f);
    float a0 = 0.f, a1 = 0.f;
    for (int base = 0; base < cnt; base += 64) {
        int rem = cnt - base;
        int nv = rem < 64 ? rem : 64;
        int didx = (lane < nv) ? (int)recs2[st + base + lane] : 0;
        int j = 0;
        for (; j + 4 <= nv; j += 4) {
            int d0 = __shfl(didx, j,     64);
            int d1 = __shfl(didx, j + 1, 64);
            int d2 = __shfl(didx, j + 2, 64);
            int d3 = __shfl(didx, j + 3, 64);
            unsigned x0 = *(const unsigned*)(xbf + (size_t)d0 * 128 + lane * 2);
            unsigned x1 = *(const unsigned*)(xbf + (size_t)d1 * 128 + lane * 2);
            unsigned x2 = *(const unsigned*)(xbf + (size_t)d2 * 128 + lane * 2);
            unsigned x3 = *(const unsigned*)(xbf + (size_t)d3 * 128 + lane * 2);
            a0 += bflo(x0) + bflo(x1) + bflo(x2) + bflo(x3);
            a1 += bfhi(x0) + bfhi(x1) + bfhi(x2) + bfhi(x3);
        }
        for (; j < nv; j++) {
            int dj = __shfl(didx, j, 64);
            unsigned xv = *(const unsigned*)(xbf + (size_t)dj * 128 + lane * 2);
            a0 += bflo(xv);
            a1 += bfhi(xv);
        }
    }
    float dg = degrees[node];
    float degc = fmaxf(dg, 1.0f);
    float inv = 1.0f / degc;
    unsigned short* row = featbf + (size_t)node * KD;
    *(unsigned int*)(row + lane * 2) = *(const unsigned int*)(xbf + (size_t)node * 128 + lane * 2);
    unsigned short o2[2] = { f2bf(a0 * inv), f2bf(a1 * inv) };
    *(unsigned int*)(row + 128 + lane * 2) = *(const unsigned int*)o2;
    if (lane < 4) {
        unsigned short t4[4] = { 0, 0, 0, 0 };
        if (lane == 0) { t4[0] = f2bf(dg); t4[1] = f2bf(dist[node] * inv); t4[2] = f2bf(1.0f); }
        *(uint2*)(row + 256 + lane * 4) = *(const uint2*)t4;
    }
}

// ---- fused MLP+LN v5: v3 geometry (782 blocks x 128 threads, 32-col ct-tiles, k-major
// conflict-free LDS) + plain single-buffered direct global->LDS staging (no reg round-trip,
// no spill). All 782 blocks co-resident (~3/CU) so serial phases overlap across blocks.
__global__ __launch_bounds__(128, 2) void fused_mlp_ln(const unsigned short* __restrict__ featbf,
                                                       const unsigned short* __restrict__ Wimg,
                                                       const float* __restrict__ x,
                                                       const float* __restrict__ b2,
                                                       const float* __restrict__ gamma,
                                                       const float* __restrict__ beta,
                                                       float* __restrict__ out) {
    __shared__ __align__(16) unsigned char lds[25600];   // single buffer: B1 17408 + B2 8192

    int tid = threadIdx.x;
    int lane = tid & 63;
    int ln = lane & 31, hi = lane >> 5;
    int wave = tid >> 6;
    int rowbase = blockIdx.x * 64 + wave * 32;
    int gr = rowbase + ln;

    // feat fragments: lane holds feat[gr][k = ks*16 + hi*8 + e]
    bf16x8 ffr[17];
    if (gr < NN) {
        const unsigned char* fp = (const unsigned char*)featbf + (size_t)gr * KB + hi * 16;
#pragma unroll
        for (int ks = 0; ks < 17; ks++)
            ffr[ks] = *(const bf16x8*)(fp + ks * 32);
    } else {
#pragma unroll
        for (int ks = 0; ks < 17; ks++) ffr[ks] = (bf16x8)(__bf16)0.0f;
    }

    f32x16 acc2[4] = {};    // out^T: lane holds out[c][gr], c = at*32 + (reg&3)+8*(reg>>2)+4*hi

    const uint4* img = (const uint4*)Wimg;     // 16 ct-tiles x 1600 uint4
    uint4* lb = (uint4*)lds;

    for (int ct = 0; ct < 16; ct++) {
        // stage tile ct: direct global->LDS copy (small live ranges, no spill)
        const uint4* src = img + ct * 1600;
        for (int idx = tid; idx < 1600; idx += 128)
            lb[idx] = src[idx];
        __syncthreads();

        // GEMM1: one 32-col tile, K=272
        f32x16 acc1 = {};
#pragma unroll
        for (int ks = 0; ks < 17; ks++) {
            bf16x8 af = *(const bf16x8*)(lds + (2 * ks + hi) * 512 + ln * 16);
            acc1 = __builtin_amdgcn_mfma_f32_32x32x16_bf16(af, ffr[ks], acc1, 0, 0, 0);
        }

        // epilogue-1: relu + pack pairs. dw[g][i] = h cols {g*8+4hi+2i, +1} of this tile
        unsigned int dw[4][2];
#pragma unroll
        for (int g = 0; g < 4; g++)
#pragma unroll
            for (int i = 0; i < 2; i++) {
                float lo = fmaxf(acc1[g * 4 + 2 * i], 0.f);
                float hf = fmaxf(acc1[g * 4 + 2 * i + 1], 0.f);
                dw[g][i] = (unsigned int)f2bf(lo) | ((unsigned int)f2bf(hf) << 16);
            }

        // GEMM2: 2 k-windows of 16; B-frag assembled via one lane<->lane^32 exchange
        const unsigned char* B2c = lds + 17408;
#pragma unroll
        for (int w = 0; w < 2; w++) {
            unsigned int sL0 = dw[2 * w][0],     sL1 = dw[2 * w][1];
            unsigned int sH0 = dw[2 * w + 1][0], sH1 = dw[2 * w + 1][1];
            unsigned int send0 = hi ? sL0 : sH0;
            unsigned int send1 = hi ? sL1 : sH1;
            unsigned int r0 = (unsigned int)__shfl_xor((int)send0, 32, 64);
            unsigned int r1 = (unsigned int)__shfl_xor((int)send1, 32, 64);
            uint4 fd;
            fd.x = hi ? r0 : sL0;
            fd.y = hi ? r1 : sL1;
            fd.z = hi ? sH0 : r0;
            fd.w = hi ? sH1 : r1;
            bf16x8 hfr = __builtin_bit_cast(bf16x8, fd);
#pragma unroll
            for (int at = 0; at < 4; at++) {
                bf16x8 a2 = *(const bf16x8*)(B2c + (2 * w + hi) * 2048 + (at * 32 + ln) * 16);
                acc2[at] = __builtin_amdgcn_mfma_f32_32x32x16_bf16(a2, hfr, acc2[at], 0, 0, 0);
            }
        }
        __syncthreads();   // all reads of this tile done before next stage overwrites
    }

    // epilogue-2: y = acc2 + b2 + x; LayerNorm across the lane pair (ln, ln+32); store
    bool rok = (gr < NN);
    float sum = 0.f, sq = 0.f;
#pragma unroll
    for (int at = 0; at < 4; at++)
#pragma unroll
        for (int g = 0; g < 4; g++) {
            int c0 = at * 32 + g * 8 + hi * 4;
            float4 bq = *(const float4*)(b2 + c0);
            float4 xq = rok ? *(const float4*)(x + (size_t)gr * 128 + c0) : make_float4(0, 0, 0, 0);
            float vb[4] = { bq.x, bq.y, bq.z, bq.w };
            float vx[4] = { xq.x, xq.y, xq.z, xq.w };
#pragma unroll
            for (int m = 0; m < 4; m++) {
                float v = acc2[at][g * 4 + m] + vb[m] + vx[m];
                acc2[at][g * 4 + m] = v;
                sum += v;
                sq += v * v;
            }
        }
    sum += __shfl_xor(sum, 32, 64);
    sq  += __shfl_xor(sq, 32, 64);
    float mu = sum * (1.0f / 128.0f);
    float var = sq * (1.0f / 128.0f) - mu * mu;
    float rs = rsqrtf(var + LN_EPS);
    if (rok) {
        float* orow = out + (size_t)gr * 128;
#pragma unroll
        for (int at = 0; at < 4; at++)
#pragma unroll
            for (int g = 0; g < 4; g++) {
                int c0 = at * 32 + g * 8 + hi * 4;
                float4 gq = *(const float4*)(gamma + c0);
                float4 be = *(const float4*)(beta + c0);
                float4 o;
                o.x = (acc2[at][g * 4 + 0] - mu) * rs * gq.x + be.x;
                o.y = (acc2[at][g * 4 + 1] - mu) * rs * gq.y + be.y;
                o.z = (acc2[at][g * 4 + 2] - mu) * rs * gq.z + be.z;
                o.w = (acc2[at][g * 4 + 3] - mu) * rs * gq.w + be.w;
                *(float4*)(orow + c0) = o;
            }
    }
}

extern "C" void kernel_launch(void* const* d_in, const int* in_sizes, int n_in,
                              void* d_out, int out_size, void* d_ws, size_t ws_size,
                              hipStream_t stream) {
    const float* x       = (const float*)d_in[0];
    const float* W1      = (const float*)d_in[1];
    const float* b1      = (const float*)d_in[2];
    const float* W2      = (const float*)d_in[3];
    const float* b2      = (const float*)d_in[4];
    const float* gamma   = (const float*)d_in[5];
    const float* beta    = (const float*)d_in[6];
    const int*   ei      = (const int*)d_in[7];
    const float* edist   = (const float*)d_in[8];
    const float* degrees = (const float*)d_in[9];
    float* out = (float*)d_out;

    char* ws = (char*)d_ws;
    size_t off = 0;
    auto alloc = [&](size_t bytes) {
        void* p = ws + off;
        off = (off + bytes + 255) & ~(size_t)255;
        return p;
    };
    unsigned* recs1         = (unsigned*)alloc((size_t)EE * 4);          // 2.56 MB
    unsigned short* recs2   = (unsigned short*)alloc((size_t)EE * 2);    // 1.28 MB
    int* start              = (int*)alloc((size_t)NN * 4);
    int* gcur               = (int*)alloc(NBK2 * 4);
    int* blocksum           = (int*)alloc(256 * 4);
    int* blockoff           = (int*)alloc(256 * 4);
    float* dist             = (float*)alloc((size_t)NN * 4);
    unsigned short* xbf     = (unsigned short*)alloc((size_t)NN * 128 * 2);
    unsigned short* featbf  = (unsigned short*)alloc((size_t)NN * KD * 2);
    unsigned short* Wimg    = (unsigned short*)alloc((size_t)204800 * 2); // 16 x 25600 B

    const int NB = (NN + 255) / 256;   // 196

    hipMemsetAsync(dist, 0, (size_t)NN * 4, stream);
    cast_x<<<3125, 256, 0, stream>>>(x, xbf);
    prep_weights<<<800, 256, 0, stream>>>(W1, b1, W2, Wimg);
    scanA<<<NB, 256, 0, stream>>>(degrees, blocksum);
    scanB<<<1, 256, 0, stream>>>(blocksum, blockoff, NB);
    scanC<<<NB, 256, 0, stream>>>(degrees, blockoff, start, gcur);
    bin_kernel<<<(EE + CH - 1) / CH, 256, 0, stream>>>(ei, edist, gcur, recs1, dist);
    subsort_kernel<<<NBK2, 256, 0, stream>>>(recs1, start, recs2);
    aggfeat_kernel<<<(NN + 3) / 4, 256, 0, stream>>>(xbf, start, degrees, recs2, dist, featbf);
    fused_mlp_ln<<<(NN + 63) / 64, 128, 0, stream>>>(featbf, Wimg, x, b2, gamma, beta, out);
}

// Round 13
// 238.928 us; speedup vs baseline: 1.5044x; 1.1230x over previous
//
#include <hip/hip_runtime.h>
#include <hip/hip_bf16.h>

#define NN 50000
#define EE 640000
#define LN_EPS 1e-5f
#define KD 272              // extended K (256 feat + deg + md + 1 + 13 zero pad)
#define KB 544              // bytes per feat row (KD*2)
#define NBK2 782            // buckets of 64 nodes (src >> 6)
#define CH 4096             // edges per binning block

typedef __bf16 bf16x8 __attribute__((ext_vector_type(8)));
typedef float f32x16 __attribute__((ext_vector_type(16)));

static __device__ __forceinline__ unsigned short f2bf(float f) {
    return __builtin_bit_cast(unsigned short, (__bf16)f);
}
static __device__ __forceinline__ float bflo(unsigned int u) {   // low bf16 of dword
    return __builtin_bit_cast(float, u << 16);
}
static __device__ __forceinline__ float bfhi(unsigned int u) {   // high bf16 of dword
    return __builtin_bit_cast(float, u & 0xffff0000u);
}

// ---- cast x to bf16 (gather source)
__global__ __launch_bounds__(256) void cast_x(const float* __restrict__ x,
                                              unsigned short* __restrict__ xbf) {
    int i = blockIdx.x * 256 + threadIdx.x;          // 8 elems per thread, 3125 blocks exact
    const float4* s = (const float4*)x + (size_t)i * 2;
    float4 a = s[0], b = s[1];
    unsigned short o[8] = { f2bf(a.x), f2bf(a.y), f2bf(a.z), f2bf(a.w),
                            f2bf(b.x), f2bf(b.y), f2bf(b.z), f2bf(b.w) };
    *(uint4*)(xbf + (size_t)i * 8) = *(const uint4*)o;
}

// ---- weight prep v6: ONE packed image per 64-col ct-tile (51200 B = LDS image, linear copy).
// Wimg[ct][0:17408 shorts]   : B1 tile [slot(34)][c(64)][e(8)] ; k=slot*8+e, col=ct*64+c
//                              k<258 -> W1[k][col] (258 rows incl deg/md); k==258 -> b1[col]; else 0
// Wimg[ct][17408:25600]      : B2 tile [slot(8)][c2(128)][e(8)] ; k=ct*64+slot*8+e -> W2[k][c2]
__global__ __launch_bounds__(256) void prep_weights(const float* __restrict__ W1,
                                                    const float* __restrict__ b1,
                                                    const float* __restrict__ W2,
                                                    unsigned short* __restrict__ Wimg) {
    int idx = blockIdx.x * 256 + threadIdx.x;        // < 204800 = 8*25600
    int ct = idx / 25600;
    int r = idx - ct * 25600;
    float v = 0.f;
    if (r < 17408) {
        int slot = r >> 9;           // 512 shorts per slot
        int c = (r >> 3) & 63;
        int e = r & 7;
        int k = slot * 8 + e;
        int col = ct * 64 + c;
        if (k < 258) v = W1[(size_t)k * 512 + col];
        else if (k == 258) v = b1[col];
    } else {
        int r2 = r - 17408;
        int slot = r2 >> 10;         // 1024 shorts per slot
        int c2 = (r2 >> 3) & 127;
        int e = r2 & 7;
        int k = ct * 64 + slot * 8 + e;
        v = W2[(size_t)k * 128 + c2];
    }
    Wimg[idx] = f2bf(v);
}

// ---- Prefix scan of int(degrees) over NN elements -> start[]; also seeds bucket cursors ----
__global__ __launch_bounds__(256) void scanA(const float* __restrict__ degrees,
                                             int* __restrict__ blocksum) {
    __shared__ int wsum[4];
    int i = blockIdx.x * 256 + threadIdx.x;
    int v = (i < NN) ? (int)(degrees[i] + 0.5f) : 0;
    int s = v;
    for (int d = 1; d < 64; d <<= 1) s += __shfl_xor(s, d, 64);
    if ((threadIdx.x & 63) == 0) wsum[threadIdx.x >> 6] = s;
    __syncthreads();
    if (threadIdx.x == 0) blocksum[blockIdx.x] = wsum[0] + wsum[1] + wsum[2] + wsum[3];
}

__global__ __launch_bounds__(256) void scanB(const int* __restrict__ blocksum,
                                             int* __restrict__ blockoff, int nb) {
    __shared__ int wsum[4];
    int tid = threadIdx.x;
    int v = (tid < nb) ? blocksum[tid] : 0;
    int lane = tid & 63, wid = tid >> 6;
    int inc = v;
    for (int d = 1; d < 64; d <<= 1) { int t = __shfl_up(inc, d, 64); if (lane >= d) inc += t; }
    if (lane == 63) wsum[wid] = inc;
    __syncthreads();
    int add = 0;
    for (int w = 0; w < wid; w++) add += wsum[w];
    inc += add;
    if (tid < nb) blockoff[tid] = inc - v;   // exclusive
}

__global__ __launch_bounds__(256) void scanC(const float* __restrict__ degrees,
                                             const int* __restrict__ blockoff,
                                             int* __restrict__ start,
                                             int* __restrict__ gcur) {
    __shared__ int wsum[4];
    int tid = threadIdx.x;
    int i = blockIdx.x * 256 + tid;
    int v = (i < NN) ? (int)(degrees[i] + 0.5f) : 0;
    int lane = tid & 63, wid = tid >> 6;
    int inc = v;
    for (int d = 1; d < 64; d <<= 1) { int t = __shfl_up(inc, d, 64); if (lane >= d) inc += t; }
    if (lane == 63) wsum[wid] = inc;
    __syncthreads();
    int add = blockoff[blockIdx.x];
    for (int w = 0; w < wid; w++) add += wsum[w];
    int excl = add + inc - v;
    if (i < NN) {
        start[i] = excl;
        if ((i & 63) == 0) gcur[i >> 6] = excl;   // bucket cursor = CSR start of its first node
    }
}

// ---- bin edges into bucket-major 4B records with LDS staging (coalesced writeout);
//      accumulate dist_sum via global atomics (200KB, L2-hot).
// record = dst(16b) | (src&63)<<16
__global__ __launch_bounds__(256) void bin_kernel(const int* __restrict__ ei,
                                                  const float* __restrict__ edist,
                                                  int* __restrict__ gcur,
                                                  unsigned* __restrict__ recs1,
                                                  float* __restrict__ dist) {
    __shared__ int cnt[NBK2], off[NBK2], gb[NBK2], c2[NBK2];
    __shared__ int wsum[4];
    __shared__ unsigned stage[CH];
    __shared__ int gtg[CH];
    int tid = threadIdx.x, lane = tid & 63, wid = tid >> 6;
    int e0 = blockIdx.x * CH;
    int nval = EE - e0; if (nval > CH) nval = CH;

    for (int i = tid; i < NBK2; i += 256) { cnt[i] = 0; c2[i] = 0; }
    __syncthreads();
#pragma unroll
    for (int k = 0; k < CH / 256; k++) {
        int e = e0 + k * 256 + tid;
        if (e < EE) atomicAdd(&cnt[ei[e] >> 6], 1);
    }
    __syncthreads();
    // exclusive scan of cnt -> off (4 elems/thread)
    {
        int v[4], s = 0;
#pragma unroll
        for (int j = 0; j < 4; j++) {
            int idx = tid * 4 + j;
            v[j] = (idx < NBK2) ? cnt[idx] : 0;
            s += v[j];
        }
        int inc = s;
        for (int d = 1; d < 64; d <<= 1) { int t = __shfl_up(inc, d, 64); if (lane >= d) inc += t; }
        if (lane == 63) wsum[wid] = inc;
        __syncthreads();
        int base = 0;
        for (int w = 0; w < wid; w++) base += wsum[w];
        int ex = base + inc - s;
#pragma unroll
        for (int j = 0; j < 4; j++) {
            int idx = tid * 4 + j;
            if (idx < NBK2) off[idx] = ex;
            ex += v[j];
        }
    }
    __syncthreads();
    // reserve global ranges
    for (int i = tid; i < NBK2; i += 256) {
        int c = cnt[i];
        gb[i] = c ? atomicAdd(&gcur[i], c) : 0;
    }
    __syncthreads();
    // stage records bucket-major; dist atomics
#pragma unroll
    for (int k = 0; k < CH / 256; k++) {
        int e = e0 + k * 256 + tid;
        if (e < EE) {
            int s = ei[e];
            int d = ei[EE + e];
            atomicAdd(dist + s, edist[e]);
            int b = s >> 6;
            int p = atomicAdd(&c2[b], 1);
            int slot = off[b] + p;
            stage[slot] = (unsigned)d | ((unsigned)(s & 63) << 16);
            gtg[slot] = gb[b] + p;
        }
    }
    __syncthreads();
    // coalesced-run writeout
    for (int i = tid; i < nval; i += 256)
        recs1[gtg[i]] = stage[i];
}

// ---- subsort: within each bucket, place records at exact per-node CSR slots (u16 dst)
__global__ __launch_bounds__(256) void subsort_kernel(const unsigned* __restrict__ recs1,
                                                      const int* __restrict__ start,
                                                      unsigned short* __restrict__ recs2) {
    __shared__ int cur[64];
    int bkt = blockIdx.x, tid = threadIdx.x;
    int bstart = start[bkt * 64];
    int bend = (bkt == NBK2 - 1) ? EE : start[(bkt + 1) * 64];
    if (tid < 64) {
        int node = bkt * 64 + tid;
        cur[tid] = (node < NN) ? start[node] : EE;
    }
    __syncthreads();
    for (int i = bstart + tid; i < bend; i += 256) {
        unsigned r = recs1[i];
        int p = atomicAdd(&cur[(r >> 16) & 63], 1);
        recs2[p] = (unsigned short)(r & 0xffffu);
    }
}

// ---- wave-per-node register aggregation + extended feat emit
__global__ __launch_bounds__(256) void aggfeat_kernel(const unsigned short* __restrict__ xbf,
                                                      const int* __restrict__ start,
                                                      const float* __restrict__ degrees,
                                                      const unsigned short* __restrict__ recs2,
                                                      const float* __restrict__ dist,
                                                      unsigned short* __restrict__ featbf) {
    int tid = threadIdx.x;
    int node = blockIdx.x * 4 + (tid >> 6);
    int lane = tid & 63;
    if (node >= NN) return;
    int st = start[node];
    int cnt = (int)(degrees[node] + 0.5f);
    float a0 = 0.f, a1 = 0.f;
    for (int base = 0; base < cnt; base += 64) {
        int rem = cnt - base;
        int nv = rem < 64 ? rem : 64;
        int didx = (lane < nv) ? (int)recs2[st + base + lane] : 0;
        int j = 0;
        for (; j + 4 <= nv; j += 4) {
            int d0 = __shfl(didx, j,     64);
            int d1 = __shfl(didx, j + 1, 64);
            int d2 = __shfl(didx, j + 2, 64);
            int d3 = __shfl(didx, j + 3, 64);
            unsigned x0 = *(const unsigned*)(xbf + (size_t)d0 * 128 + lane * 2);
            unsigned x1 = *(const unsigned*)(xbf + (size_t)d1 * 128 + lane * 2);
            unsigned x2 = *(const unsigned*)(xbf + (size_t)d2 * 128 + lane * 2);
            unsigned x3 = *(const unsigned*)(xbf + (size_t)d3 * 128 + lane * 2);
            a0 += bflo(x0) + bflo(x1) + bflo(x2) + bflo(x3);
            a1 += bfhi(x0) + bfhi(x1) + bfhi(x2) + bfhi(x3);
        }
        for (; j < nv; j++) {
            int dj = __shfl(didx, j, 64);
            unsigned xv = *(const unsigned*)(xbf + (size_t)dj * 128 + lane * 2);
            a0 += bflo(xv);
            a1 += bfhi(xv);
        }
    }
    float dg = degrees[node];
    float degc = fmaxf(dg, 1.0f);
    float inv = 1.0f / degc;
    unsigned short* row = featbf + (size_t)node * KD;
    *(unsigned int*)(row + lane * 2) = *(const unsigned int*)(xbf + (size_t)node * 128 + lane * 2);
    unsigned short o2[2] = { f2bf(a0 * inv), f2bf(a1 * inv) };
    *(unsigned int*)(row + 128 + lane * 2) = *(const unsigned int*)o2;
    if (lane < 4) {
        unsigned short t4[4] = { 0, 0, 0, 0 };
        if (lane == 0) { t4[0] = f2bf(dg); t4[1] = f2bf(dist[node] * inv); t4[2] = f2bf(1.0f); }
        *(uint2*)(row + 256 + lane * 4) = *(const uint2*)t4;
    }
}

// ---- fused MLP+LN v6: v2 geometry (391 blocks x 256 threads, 4 waves x 32 rows,
// 8 ct-tiles of 64 cols, 2 interleaved GEMM1 chains) + v5's k-major conflict-free
// packed-image staging (direct global->LDS copy, no swizzle, no VGPR round-trip arrays).
__global__ __launch_bounds__(256, 2) void fused_mlp_ln(const unsigned short* __restrict__ featbf,
                                                       const unsigned short* __restrict__ Wimg,
                                                       const float* __restrict__ x,
                                                       const float* __restrict__ b2,
                                                       const float* __restrict__ gamma,
                                                       const float* __restrict__ beta,
                                                       float* __restrict__ out) {
    __shared__ __align__(16) unsigned char lds[51200];   // B1 [34][64]x16B + B2 [8][128]x16B

    int tid = threadIdx.x;
    int wave = tid >> 6, lane = tid & 63;
    int ln = lane & 31, hi = lane >> 5;
    int rowbase = blockIdx.x * 128 + wave * 32;
    int gr = rowbase + ln;

    // feat fragments: lane holds feat[gr][k = ks*16 + hi*8 + e]
    bf16x8 ffr[17];
    if (gr < NN) {
        const unsigned char* fp = (const unsigned char*)featbf + (size_t)gr * KB + hi * 16;
#pragma unroll
        for (int ks = 0; ks < 17; ks++)
            ffr[ks] = *(const bf16x8*)(fp + ks * 32);
    } else {
#pragma unroll
        for (int ks = 0; ks < 17; ks++) ffr[ks] = (bf16x8)(__bf16)0.0f;
    }

    f32x16 acc2[4] = {};    // out^T: lane holds out[c][gr], c = at*32 + (reg&3)+8*(reg>>2)+4*hi

    const uint4* img = (const uint4*)Wimg;     // 8 ct-tiles x 3200 uint4
    uint4* lb = (uint4*)lds;

    for (int ct = 0; ct < 8; ct++) {
        // stage tile ct: direct linear global->LDS copy (k-major image, conflict-free reads)
        const uint4* src = img + ct * 3200;
        for (int idx = tid; idx < 3200; idx += 256)
            lb[idx] = src[idx];
        __syncthreads();

        // GEMM1: two interleaved 32-col chains, K=272
        f32x16 acc1[2] = {};
#pragma unroll
        for (int ks = 0; ks < 17; ks++) {
#pragma unroll
            for (int t = 0; t < 2; t++) {
                bf16x8 af = *(const bf16x8*)(lds + (2 * ks + hi) * 1024 + (t * 32 + ln) * 16);
                acc1[t] = __builtin_amdgcn_mfma_f32_32x32x16_bf16(af, ffr[ks], acc1[t], 0, 0, 0);
            }
        }

        // epilogue-1: relu + pack pairs. dw[t][g][i] = h cols {ct*64+t*32+g*8+4hi+2i, +1}
        unsigned int dw[2][4][2];
#pragma unroll
        for (int t = 0; t < 2; t++)
#pragma unroll
            for (int g = 0; g < 4; g++)
#pragma unroll
                for (int i = 0; i < 2; i++) {
                    float lo = fmaxf(acc1[t][g * 4 + 2 * i], 0.f);
                    float hf = fmaxf(acc1[t][g * 4 + 2 * i + 1], 0.f);
                    dw[t][g][i] = (unsigned int)f2bf(lo) | ((unsigned int)f2bf(hf) << 16);
                }

        // GEMM2: 4 k-windows of 16; B-frag assembled via one lane<->lane^32 exchange
        const unsigned char* B2c = lds + 34816;
#pragma unroll
        for (int t = 0; t < 2; t++)
#pragma unroll
            for (int w = 0; w < 2; w++) {
                int ks2 = t * 2 + w;
                unsigned int sL0 = dw[t][2 * w][0],     sL1 = dw[t][2 * w][1];
                unsigned int sH0 = dw[t][2 * w + 1][0], sH1 = dw[t][2 * w + 1][1];
                unsigned int send0 = hi ? sL0 : sH0;
                unsigned int send1 = hi ? sL1 : sH1;
                unsigned int r0 = (unsigned int)__shfl_xor((int)send0, 32, 64);
                unsigned int r1 = (unsigned int)__shfl_xor((int)send1, 32, 64);
                uint4 fd;
                fd.x = hi ? r0 : sL0;
                fd.y = hi ? r1 : sL1;
                fd.z = hi ? sH0 : r0;
                fd.w = hi ? sH1 : r1;
                bf16x8 hfr = __builtin_bit_cast(bf16x8, fd);
#pragma unroll
                for (int at = 0; at < 4; at++) {
                    bf16x8 a2 = *(const bf16x8*)(B2c + (2 * ks2 + hi) * 2048 + (at * 32 + ln) * 16);
                    acc2[at] = __builtin_amdgcn_mfma_f32_32x32x16_bf16(a2, hfr, acc2[at], 0, 0, 0);
                }
            }
        __syncthreads();   // all reads of this tile done before next stage overwrites
    }

    // epilogue-2: y = acc2 + b2 + x; LayerNorm across the lane pair (ln, ln+32); store
    bool rok = (gr < NN);
    float sum = 0.f, sq = 0.f;
#pragma unroll
    for (int at = 0; at < 4; at++)
#pragma unroll
        for (int g = 0; g < 4; g++) {
            int c0 = at * 32 + g * 8 + hi * 4;
            float4 bq = *(const float4*)(b2 + c0);
            float4 xq = rok ? *(const float4*)(x + (size_t)gr * 128 + c0) : make_float4(0, 0, 0, 0);
            float vb[4] = { bq.x, bq.y, bq.z, bq.w };
            float vx[4] = { xq.x, xq.y, xq.z, xq.w };
#pragma unroll
            for (int m = 0; m < 4; m++) {
                float v = acc2[at][g * 4 + m] + vb[m] + vx[m];
                acc2[at][g * 4 + m] = v;
                sum += v;
                sq += v * v;
            }
        }
    sum += __shfl_xor(sum, 32, 64);
    sq  += __shfl_xor(sq, 32, 64);
    float mu = sum * (1.0f / 128.0f);
    float var = sq * (1.0f / 128.0f) - mu * mu;
    float rs = rsqrtf(var + LN_EPS);
    if (rok) {
        float* orow = out + (size_t)gr * 128;
#pragma unroll
        for (int at = 0; at < 4; at++)
#pragma unroll
            for (int g = 0; g < 4; g++) {
                int c0 = at * 32 + g * 8 + hi * 4;
                float4 gq = *(const float4*)(gamma + c0);
                float4 be = *(const float4*)(beta + c0);
                float4 o;
                o.x = (acc2[at][g * 4 + 0] - mu) * rs * gq.x + be.x;
                o.y = (acc2[at][g * 4 + 1] - mu) * rs * gq.y + be.y;
                o.z = (acc2[at][g * 4 + 2] - mu) * rs * gq.z + be.z;
                o.w = (acc2[at][g * 4 + 3] - mu) * rs * gq.w + be.w;
                *(float4*)(orow + c0) = o;
            }
    }
}

extern "C" void kernel_launch(void* const* d_in, const int* in_sizes, int n_in,
                              void* d_out, int out_size, void* d_ws, size_t ws_size,
                              hipStream_t stream) {
    const float* x       = (const float*)d_in[0];
    const float* W1      = (const float*)d_in[1];
    const float* b1      = (const float*)d_in[2];
    const float* W2      = (const float*)d_in[3];
    const float* b2      = (const float*)d_in[4];
    const float* gamma   = (const float*)d_in[5];
    const float* beta    = (const float*)d_in[6];
    const int*   ei      = (const int*)d_in[7];
    const float* edist   = (const float*)d_in[8];
    const float* degrees = (const float*)d_in[9];
    float* out = (float*)d_out;

    char* ws = (char*)d_ws;
    size_t off = 0;
    auto alloc = [&](size_t bytes) {
        void* p = ws + off;
        off = (off + bytes + 255) & ~(size_t)255;
        return p;
    };
    unsigned* recs1         = (unsigned*)alloc((size_t)EE * 4);          // 2.56 MB
    unsigned short* recs2   = (unsigned short*)alloc((size_t)EE * 2);    // 1.28 MB
    int* start              = (int*)alloc((size_t)NN * 4);
    int* gcur               = (int*)alloc(NBK2 * 4);
    int* blocksum           = (int*)alloc(256 * 4);
    int* blockoff           = (int*)alloc(256 * 4);
    float* dist             = (float*)alloc((size_t)NN * 4);
    unsigned short* xbf     = (unsigned short*)alloc((size_t)NN * 128 * 2);
    unsigned short* featbf  = (unsigned short*)alloc((size_t)NN * KD * 2);
    unsigned short* Wimg    = (unsigned short*)alloc((size_t)204800 * 2); // 8 x 51200 B

    const int NB = (NN + 255) / 256;   // 196

    hipMemsetAsync(dist, 0, (size_t)NN * 4, stream);
    cast_x<<<3125, 256, 0, stream>>>(x, xbf);
    prep_weights<<<800, 256, 0, stream>>>(W1, b1, W2, Wimg);
    scanA<<<NB, 256, 0, stream>>>(degrees, blocksum);
    scanB<<<1, 256, 0, stream>>>(blocksum, blockoff, NB);
    scanC<<<NB, 256, 0, stream>>>(degrees, blockoff, start, gcur);
    bin_kernel<<<(EE + CH - 1) / CH, 256, 0, stream>>>(ei, edist, gcur, recs1, dist);
    subsort_kernel<<<NBK2, 256, 0, stream>>>(recs1, start, recs2);
    aggfeat_kernel<<<(NN + 3) / 4, 256, 0, stream>>>(xbf, start, degrees, recs2, dist, featbf);
    fused_mlp_ln<<<(NN + 127) / 128, 256, 0, stream>>>(featbf, Wimg, x, b2, gamma, beta, out);
}